// Round 3
// baseline (131.586 us; speedup 1.0000x reference)
//
#include <hip/hip_runtime.h>
#include <math.h>

#define TAU_C      0.69314718055994530942f   // log(2)
#define LAM_C      0.25f
#define NEG_INV_E  -0.36787944117144232160   // -1/e (double)
#define INV_BATCH  (1.0f / 12.0f)

#define TBL_N      2048                      // cells
#define TBL_LMAX   16.0f
#define TBL_SCALE  (TBL_N / TBL_LMAX)        // 128 per unit l
// kink: l0 = tau - 1/(2e); below it F is exactly linear: F = e*(l-tau)+0.25
#define L0_D       0.50925752433880320442

// ---------------- table build (runs once per call, 2049 knots, fp64) -----
__device__ double lambertw_d(double y) {
    double w = (y < 1.0)
        ? (-1.0 + sqrt(fmax(2.0 * (2.718281828459045235 * y + 1.0), 0.0)))
        : log1p(y);
#pragma unroll
    for (int it = 0; it < 12; ++it) {
        double ew  = exp(w);
        double f   = fma(w, ew, -y);
        double wp1 = w + 1.0;
        double den = ew * wp1 - (w + 2.0) * f / (2.0 * wp1 + 1e-300);
        double wn  = w - f / den;
        w = (f != 0.0) ? wn : w;
    }
    return w;
}

__device__ double F_knot(double l) {
    if (l < L0_D)
        return 2.718281828459045235 * (l - 0.69314718055994530942) + 0.25;
    double y = 2.0 * (l - 0.69314718055994530942);
    double w = lambertw_d(fmax(y, NEG_INV_E));
    return 0.5 * w + 0.25 * w * w;      // = (l-tau)*exp(-W) + lam*W^2
}

__global__ __launch_bounds__(256) void superloss_table(float2* __restrict__ tbl,
                                                       float* __restrict__ out) {
    int i = blockIdx.x * blockDim.x + threadIdx.x;
    if (i == 0) out[0] = 0.0f;          // d_out is poisoned; zero for atomics
    if (i > TBL_N) return;
    double h  = (double)TBL_LMAX / TBL_N;
    double f0 = F_knot(i * h);
    double f1 = F_knot((i + 1) * h);
    tbl[i] = make_float2((float)f0, (float)f1);
}

// ---------------- main pass ---------------------------------------------
__shared__ float2 s_tbl[TBL_N + 1];      // 16.4 KB

__device__ __forceinline__ float row_fast(float a, float b, float c, int label) {
    float s  = __expf(a) + __expf(b) + __expf(c);
    float xl = (label == 0) ? a : ((label == 1) ? b : c);
    float l  = __logf(s) - xl;

    float u = fminf(fmaxf(l * TBL_SCALE, 0.0f), (float)TBL_N - 0.001f);
    int   i = (int)u;
    float f = u - (float)i;
    float2 t = s_tbl[i];                 // one ds_read_b64
    return fmaf(f, t.y - t.x, t.x);
}

__global__ __launch_bounds__(256, 8) void superloss_partial(
        const float* __restrict__ x,
        const float2* __restrict__ gtbl,
        const int* __restrict__ pn0,
        const int* __restrict__ pn1,
        float* __restrict__ out,
        int nrows) {
    for (int i = threadIdx.x; i <= TBL_N; i += 256)
        s_tbl[i] = gtbl[i];
    __syncthreads();

    const int n0  = *pn0;
    const int n01 = n0 + *pn1;

    const int nq     = nrows >> 2;
    const int gid    = blockIdx.x * blockDim.x + threadIdx.x;
    const int stride = gridDim.x * blockDim.x;

    float acc = 0.0f;

    for (int q = gid; q < nq; q += stride) {
        const float4* p = (const float4*)x + 3 * (size_t)q;
        float4 f0 = p[0];
        float4 f1 = p[1];
        float4 f2 = p[2];
        int r0 = q << 2;
        int l0 = (r0     >= n0) + (r0     >= n01);
        int l1 = (r0 + 1 >= n0) + (r0 + 1 >= n01);
        int l2 = (r0 + 2 >= n0) + (r0 + 2 >= n01);
        int l3 = (r0 + 3 >= n0) + (r0 + 3 >= n01);
        acc += row_fast(f0.x, f0.y, f0.z, l0);
        acc += row_fast(f0.w, f1.x, f1.y, l1);
        acc += row_fast(f1.z, f1.w, f2.x, l2);
        acc += row_fast(f2.y, f2.z, f2.w, l3);
    }

    for (int r = (nq << 2) + gid; r < nrows; r += stride) {
        float a = x[3 * (size_t)r];
        float b = x[3 * (size_t)r + 1];
        float c = x[3 * (size_t)r + 2];
        int lab = (r >= n0) + (r >= n01);
        acc += row_fast(a, b, c, lab);
    }

    // wave + block reduce, then one atomic per block
#pragma unroll
    for (int off = 32; off > 0; off >>= 1)
        acc += __shfl_down(acc, off, 64);
    __shared__ float sacc[4];
    int lane = threadIdx.x & 63;
    int wv   = threadIdx.x >> 6;
    if (lane == 0) sacc[wv] = acc;
    __syncthreads();
    if (threadIdx.x == 0) {
        float s = (sacc[0] + sacc[1] + sacc[2] + sacc[3]) * INV_BATCH;
        atomicAdd(out, s);
    }
}

extern "C" void kernel_launch(void* const* d_in, const int* in_sizes, int n_in,
                              void* d_out, int out_size, void* d_ws, size_t ws_size,
                              hipStream_t stream) {
    const float* x   = (const float*)d_in[0];
    const int*   pn0 = (const int*)d_in[1];
    const int*   pn1 = (const int*)d_in[2];

    const int nrows = in_sizes[0] / 3;

    float2* gtbl = (float2*)d_ws;        // (TBL_N+1) float2 = 16.4 KB
    float*  out  = (float*)d_out;

    superloss_table<<<(TBL_N + 256) / 256, 256, 0, stream>>>(gtbl, out);
    superloss_partial<<<2048, 256, 0, stream>>>(x, gtbl, pn0, pn1, out, nrows);
}

// Round 4
// 107.570 us; speedup vs baseline: 1.2233x; 1.2233x over previous
//
#include <hip/hip_runtime.h>
#include <math.h>

#define TBL_N     1024
#define KIDX      44.36141955583649f     // (TBL_N/16) * ln2 — maps l to table index
#define LOG2E     1.44269504088896340736f
#define INV_BATCH (1.0f / 12.0f)

// ================= compile-time table: F(l) on l in [0,16], 1025 knots ====
// F(l) = (l-tau)*exp(-W(y)) + 0.25*W^2, y = 0.5*max(-2/e, 4(l-tau))
//      = e*(l-tau) + 0.25                      for l <  l0 = tau - 1/(2e)
//      = ((1+W(2(l-tau)))^2 - 1) / 4           for l >= l0   (exact identity)
struct TblData { float v[TBL_N + 1]; };

constexpr double k_ln2 = 0.69314718055994530942;
constexpr double k_e   = 2.71828182845904523536;

constexpr double cexp(double x) {                 // |x| <= ~4 here
    double t = x * 1.44269504088896340736;
    int n = (int)(t + (t >= 0 ? 0.5 : -0.5));
    double r = x - (double)n * k_ln2;
    double s = 1.0, term = 1.0;
    for (int i = 1; i <= 13; ++i) { term *= r / i; s += term; }
    double p = 1.0;
    if (n >= 0) for (int i = 0; i <  n; ++i) p *= 2.0;
    else        for (int i = 0; i < -n; ++i) p *= 0.5;
    return s * p;
}
constexpr double csqrt_(double x) {
    double r = x > 1.0 ? x : 1.0;
    for (int i = 0; i < 24; ++i) r = 0.5 * (r + x / r);
    return r;
}
constexpr double clog_(double x) {                // x in [1, ~32]
    int n = 0; double m = x;
    while (m >= 2.0) { m *= 0.5; ++n; }
    while (m <  1.0) { m *= 2.0; --n; }
    double z = (m - 1.0) / (m + 1.0), z2 = z * z, s = 0.0, t = z;
    for (int i = 0; i < 17; ++i) { s += t / (2 * i + 1); t *= z2; }
    return 2.0 * s + (double)n * k_ln2;
}
constexpr TblData make_table() {
    TblData T{};
    for (int i = 0; i <= TBL_N; ++i) {
        double l   = (double)i * (16.0 / TBL_N);
        double tau = k_ln2;
        double l0  = tau - 1.0 / (2.0 * k_e);
        double F;
        if (l < l0) {
            F = k_e * (l - tau) + 0.25;
        } else {
            double y = 2.0 * (l - tau);
            double ylim = -1.0 / k_e;
            if (y < ylim) y = ylim;
            double w = (y < 3.0) ? (csqrt_(2.0 * (k_e * y + 1.0)) - 1.0)
                                 : clog_(y);
            for (int it = 0; it < 4; ++it) {      // Halley, cubic convergence
                double ew  = cexp(w);
                double f   = w * ew - y;
                double wp1 = w + 1.0;
                double den = ew * wp1 - (w + 2.0) * f / (2.0 * wp1 + 1e-300);
                if (f != 0.0) w -= f / den;
            }
            F = 0.25 * ((1.0 + w) * (1.0 + w) - 1.0);
        }
        T.v[i] = (float)F;
    }
    return T;
}
__device__ __constant__ TblData c_tbl = make_table();

// ================= main pass =============================================
__shared__ float s_tbl[TBL_N + 1];                // 4.1 KB

__device__ __forceinline__ float row_fast(float a, float b, float c, int label) {
    float a2 = a * LOG2E, b2 = b * LOG2E, c2 = c * LOG2E;
    float s  = exp2f(a2) + exp2f(b2) + exp2f(c2);     // native v_exp_f32
    float xl2 = (label == 0) ? a2 : ((label == 1) ? b2 : c2);
    float u = (__log2f(s) - xl2) * KIDX;              // l * TBL_N/16
    u = fminf(fmaxf(u, 0.0f), (float)TBL_N - 0.001f);
    int   i = (int)u;
    float f = u - (float)i;
    float t0 = s_tbl[i];                              // two ds_read_b32
    float t1 = s_tbl[i + 1];
    return fmaf(f, t1 - t0, t0);
}

__device__ __forceinline__ float block_reduce(float acc) {
#pragma unroll
    for (int off = 32; off > 0; off >>= 1)
        acc += __shfl_down(acc, off, 64);
    __shared__ float sacc[4];
    int lane = threadIdx.x & 63;
    int wv   = threadIdx.x >> 6;
    if (lane == 0) sacc[wv] = acc;
    __syncthreads();
    float s = 0.0f;
    if (threadIdx.x == 0)
        s = sacc[0] + sacc[1] + sacc[2] + sacc[3];
    return s;
}

__global__ __launch_bounds__(256) void superloss_partial(
        const float* __restrict__ x,
        const int* __restrict__ pn0,
        const int* __restrict__ pn1,
        float* __restrict__ partial,
        int nrows) {
    for (int i = threadIdx.x; i <= TBL_N; i += 256)
        s_tbl[i] = c_tbl.v[i];
    __syncthreads();

    const int n0  = *pn0;
    const int n01 = n0 + *pn1;

    const int nq     = nrows >> 2;
    const int gid    = blockIdx.x * blockDim.x + threadIdx.x;
    const int stride = gridDim.x * blockDim.x;

    float acc = 0.0f;

    for (int q = gid; q < nq; q += stride) {
        const float4* p = (const float4*)x + 3 * (size_t)q;
        float4 f0 = p[0];
        float4 f1 = p[1];
        float4 f2 = p[2];
        int r0 = q << 2;
        int l0 = (r0     >= n0) + (r0     >= n01);
        int l1 = (r0 + 1 >= n0) + (r0 + 1 >= n01);
        int l2 = (r0 + 2 >= n0) + (r0 + 2 >= n01);
        int l3 = (r0 + 3 >= n0) + (r0 + 3 >= n01);
        acc += row_fast(f0.x, f0.y, f0.z, l0);
        acc += row_fast(f0.w, f1.x, f1.y, l1);
        acc += row_fast(f1.z, f1.w, f2.x, l2);
        acc += row_fast(f2.y, f2.z, f2.w, l3);
    }

    for (int r = (nq << 2) + gid; r < nrows; r += stride) {
        float a = x[3 * (size_t)r];
        float b = x[3 * (size_t)r + 1];
        float c = x[3 * (size_t)r + 2];
        int lab = (r >= n0) + (r >= n01);
        acc += row_fast(a, b, c, lab);
    }

    float s = block_reduce(acc);
    if (threadIdx.x == 0)
        partial[blockIdx.x] = s;
}

__global__ __launch_bounds__(256) void superloss_final(
        const float* __restrict__ partial,
        int np,
        float* __restrict__ out) {
    float acc = 0.0f;
    for (int i = threadIdx.x; i < np; i += 256)
        acc += partial[i];
    float s = block_reduce(acc);
    if (threadIdx.x == 0)
        out[0] = s * INV_BATCH;
}

extern "C" void kernel_launch(void* const* d_in, const int* in_sizes, int n_in,
                              void* d_out, int out_size, void* d_ws, size_t ws_size,
                              hipStream_t stream) {
    const float* x   = (const float*)d_in[0];
    const int*   pn0 = (const int*)d_in[1];
    const int*   pn1 = (const int*)d_in[2];

    const int nrows = in_sizes[0] / 3;

    int nblk = 2048;
    size_t need = (size_t)nblk * sizeof(float);
    if (ws_size < need) {
        nblk = (int)(ws_size / sizeof(float));
        if (nblk < 1) nblk = 1;
    }

    float* partial = (float*)d_ws;
    superloss_partial<<<nblk, 256, 0, stream>>>(x, pn0, pn1, partial, nrows);
    superloss_final<<<1, 256, 0, stream>>>(partial, nblk, (float*)d_out);
}